// Round 1
// baseline (430.608 us; speedup 1.0000x reference)
//
#include <hip/hip_runtime.h>
#include <hip/hip_bf16.h>

typedef unsigned short u16;
typedef unsigned int   u32;

using f32x4 = __attribute__((ext_vector_type(4))) float;
using s16x8 = __attribute__((ext_vector_type(8))) short;
using b16x8 = __attribute__((ext_vector_type(8))) __bf16;

#define SCALE 0.03125f   // 1/sqrt(64)/4

__device__ __forceinline__ f32x4 mfma16(s16x8 a, s16x8 b, f32x4 c) {
  return __builtin_amdgcn_mfma_f32_16x16x32_bf16(
      __builtin_bit_cast(b16x8, a), __builtin_bit_cast(b16x8, b), c, 0, 0, 0);
}

__device__ __forceinline__ u16 f2bf(float f) {
  u32 u = __builtin_bit_cast(u32, f);
  u = (u + 0x7FFFu + ((u >> 16) & 1u)) >> 16;
  return (u16)u;
}
__device__ __forceinline__ float bf2f(u16 b) {
  return __builtin_bit_cast(float, ((u32)b) << 16);
}

// async global->LDS, 16B per lane; LDS dest = wave-uniform base + lane*16
__device__ __forceinline__ void gload16(const void* g, void* l) {
  __builtin_amdgcn_global_load_lds(
      (const __attribute__((address_space(1))) u32*)g,
      (__attribute__((address_space(3))) u32*)l, 16, 0, 0);
}

// ---------------- fp32 -> bf16 convert ----------------
__global__ void cvt(const float* __restrict__ in, u16* __restrict__ out, int n4) {
  int i = blockIdx.x * blockDim.x + threadIdx.x;
  int stride = gridDim.x * blockDim.x;
  for (; i < n4; i += stride) {
    float4 v = ((const float4*)in)[i];
    ushort4 o;
    o.x = f2bf(v.x); o.y = f2bf(v.y); o.z = f2bf(v.z); o.w = f2bf(v.w);
    ((ushort4*)out)[i] = o;
  }
}

// ---------------- GEMM: C[M,N] = A[M,K] @ B[N,K]^T  (both bf16, row-major) ----
// EPI==0: qkv epilogue (add q/v bias, scatter to q[B,H,L,D], k[B,H,L,D], vT[B,H,D,L], bf16)
// EPI==1: proj epilogue (add b_proj, fp32 out row-major [M,N])
template<int EPI>
__global__ __launch_bounds__(256)
void gemm_bt(const u16* __restrict__ A, const u16* __restrict__ Bm,
             int M, int N, int K,
             const float* __restrict__ bias0, const float* __restrict__ bias1,
             u16* __restrict__ oq, u16* __restrict__ ok, u16* __restrict__ ov,
             float* __restrict__ outf)
{
  __shared__ u16 As[128 * 32];
  __shared__ u16 Bs[128 * 32];

  const int tid  = threadIdx.x;
  const int w    = tid >> 6;
  const int lane = tid & 63;
  const int lr   = lane & 15;
  const int lg   = lane >> 4;
  const int wr   = w >> 1, wc = w & 1;

  const int bm = blockIdx.y, bn = blockIdx.x;

  f32x4 acc[4][4];
#pragma unroll
  for (int i = 0; i < 4; ++i)
#pragma unroll
    for (int j = 0; j < 4; ++j) acc[i][j] = (f32x4){0.f, 0.f, 0.f, 0.f};

  const int rowA = bm * 128 + (tid >> 2);
  const int rowB = bn * 128 + (tid >> 2);
  const int colk = (tid & 3) * 8;

  for (int kt = 0; kt < K; kt += 32) {
    __syncthreads();
    {
      const u16* ga = A  + (long)rowA * K + kt + colk;
      const u16* gb = Bm + (long)rowB * K + kt + colk;
      u16* la = As + w * 512;
      u16* lb = Bs + w * 512;
      gload16(ga,            la);
      gload16(ga + 64 * K,   la + 2048);
      gload16(gb,            lb);
      gload16(gb + 64 * K,   lb + 2048);
    }
    __syncthreads();

    s16x8 af[4], bfr[4];
#pragma unroll
    for (int mi = 0; mi < 4; ++mi)
      af[mi] = *(const s16x8*)(As + (wr * 64 + mi * 16 + lr) * 32 + lg * 8);
#pragma unroll
    for (int ni = 0; ni < 4; ++ni)
      bfr[ni] = *(const s16x8*)(Bs + (wc * 64 + ni * 16 + lr) * 32 + lg * 8);
#pragma unroll
    for (int mi = 0; mi < 4; ++mi)
#pragma unroll
      for (int ni = 0; ni < 4; ++ni)
        acc[mi][ni] = mfma16(af[mi], bfr[ni], acc[mi][ni]);
  }

  const int gm0 = bm * 128 + wr * 64;
  const int gn0 = bn * 128 + wc * 64;

#pragma unroll
  for (int mi = 0; mi < 4; ++mi) {
#pragma unroll
    for (int ni = 0; ni < 4; ++ni) {
      const int col  = gn0 + ni * 16 + lr;
      const int row0 = gm0 + mi * 16 + lg * 4;
      if (EPI == 0) {
        const int which = col >> 10;          // 0=q 1=k 2=v
        const int cj    = col & 1023;
        const float badd = (which == 0) ? bias0[cj] : (which == 2 ? bias1[cj] : 0.f);
        const int h = cj >> 6, d = cj & 63;
#pragma unroll
        for (int r = 0; r < 4; ++r) {
          const int rowg = row0 + r;           // = b*2048 + l
          const int b = rowg >> 11, l = rowg & 2047;
          const int bh = b * 16 + h;
          const u16 o = f2bf(acc[mi][ni][r] + badd);
          if (which == 0)      oq[(bh * 2048 + l) * 64 + d] = o;
          else if (which == 1) ok[(bh * 2048 + l) * 64 + d] = o;
          else                 ov[(bh * 64 + d) * 2048 + l] = o;   // transposed V
        }
      } else {
        const float badd = bias0[col];
#pragma unroll
        for (int r = 0; r < 4; ++r)
          outf[(long)(row0 + r) * N + col] = acc[mi][ni][r] + badd;
      }
    }
  }
}

// ---------------- flash attention ----------------
// grid: x = L/64 (q tiles), y = B*H.  256 threads = 4 waves, 16 q-rows/wave.
__global__ __launch_bounds__(256)
void flash_attn(const u16* __restrict__ qbuf, const u16* __restrict__ kbuf,
                const u16* __restrict__ vtbuf, const u16* __restrict__ biasb,
                u16* __restrict__ oup)
{
  __shared__ u16 Qs[64 * 64];
  __shared__ u16 Ks[64 * 64];
  __shared__ u16 Vs[64 * 64];          // holds V^T tile: [d][key]
  __shared__ u16 Ps[4][16 * 72];       // per-wave P, padded stride 72 elems

  const int tid  = threadIdx.x;
  const int w    = tid >> 6;
  const int lane = tid & 63;
  const int lr   = lane & 15;
  const int lg   = lane >> 4;
  const int bh   = blockIdx.y;
  const int qb0  = blockIdx.x * 64;
  const int base = bh * (2048 * 64);

  // stage Q tile (contiguous 8KB)
  gload16(qbuf + base + qb0 * 64 + tid * 8,        Qs + w * 512);
  gload16(qbuf + base + qb0 * 64 + 2048 + tid * 8, Qs + 2048 + w * 512);
  __syncthreads();

  const s16x8 qf0 = *(const s16x8*)(Qs + (w * 16 + lr) * 64 + lg * 8);
  const s16x8 qf1 = *(const s16x8*)(Qs + (w * 16 + lr) * 64 + 32 + lg * 8);

  float m_run[4], l_run[4];
  f32x4 oacc[4];
#pragma unroll
  for (int r = 0; r < 4; ++r) { m_run[r] = -1e30f; l_run[r] = 0.f; }
#pragma unroll
  for (int db = 0; db < 4; ++db) oacc[db] = (f32x4){0.f, 0.f, 0.f, 0.f};

  const int qrow0 = qb0 + w * 16 + lg * 4;

  for (int kt = 0; kt < 2048; kt += 64) {
    __syncthreads();
    // K tile: contiguous 8KB.  V^T tile: 64 rows (d) x 64 keys, row stride 2048.
    gload16(kbuf + base + kt * 64 + tid * 8,        Ks + w * 512);
    gload16(kbuf + base + kt * 64 + 2048 + tid * 8, Ks + 2048 + w * 512);
    gload16(vtbuf + base + (tid >> 3) * 2048 + kt + (tid & 7) * 8,         Vs + w * 512);
    gload16(vtbuf + base + (tid >> 3) * 2048 + 65536 + kt + (tid & 7) * 8, Vs + 2048 + w * 512);
    __syncthreads();

    // S = Q K^T  (4 key-blocks of 16)
    f32x4 s[4];
#pragma unroll
    for (int kb = 0; kb < 4; ++kb) {
      const s16x8 kf0 = *(const s16x8*)(Ks + (kb * 16 + lr) * 64 + lg * 8);
      const s16x8 kf1 = *(const s16x8*)(Ks + (kb * 16 + lr) * 64 + 32 + lg * 8);
      f32x4 t = (f32x4){0.f, 0.f, 0.f, 0.f};
      t = mfma16(qf0, kf0, t);
      t = mfma16(qf1, kf1, t);
      s[kb] = t;
    }

    // scale + bias, online softmax (rows live in the 16-lane column group)
    float p[4][4];
    float mt[4] = {-1e30f, -1e30f, -1e30f, -1e30f};
#pragma unroll
    for (int kb = 0; kb < 4; ++kb) {
      const int kc = kt + kb * 16 + lr;
#pragma unroll
      for (int r = 0; r < 4; ++r) {
        const float sc = s[kb][r] * SCALE + bf2f(biasb[(qrow0 + r) * 2048 + kc]);
        p[kb][r] = sc;
        mt[r] = fmaxf(mt[r], sc);
      }
    }
#pragma unroll
    for (int xm = 1; xm < 16; xm <<= 1)
#pragma unroll
      for (int r = 0; r < 4; ++r)
        mt[r] = fmaxf(mt[r], __shfl_xor(mt[r], xm, 64));

    float scl[4], rs[4];
#pragma unroll
    for (int r = 0; r < 4; ++r) {
      const float mn = fmaxf(m_run[r], mt[r]);
      scl[r] = __expf(m_run[r] - mn);
      m_run[r] = mn;
    }
#pragma unroll
    for (int kb = 0; kb < 4; ++kb)
#pragma unroll
      for (int r = 0; r < 4; ++r)
        p[kb][r] = __expf(p[kb][r] - m_run[r]);
#pragma unroll
    for (int r = 0; r < 4; ++r) rs[r] = p[0][r] + p[1][r] + p[2][r] + p[3][r];
#pragma unroll
    for (int xm = 1; xm < 16; xm <<= 1)
#pragma unroll
      for (int r = 0; r < 4; ++r)
        rs[r] += __shfl_xor(rs[r], xm, 64);
#pragma unroll
    for (int r = 0; r < 4; ++r) l_run[r] = l_run[r] * scl[r] + rs[r];
#pragma unroll
    for (int db = 0; db < 4; ++db)
#pragma unroll
      for (int r = 0; r < 4; ++r)
        oacc[db][r] *= scl[r];

    // P -> LDS (wave-private), then read back as A-fragments
#pragma unroll
    for (int kb = 0; kb < 4; ++kb)
#pragma unroll
      for (int r = 0; r < 4; ++r)
        Ps[w][(lg * 4 + r) * 72 + kb * 16 + lr] = f2bf(p[kb][r]);
    asm volatile("s_waitcnt lgkmcnt(0)" ::: "memory");
    const s16x8 pa0 = *(const s16x8*)(&Ps[w][lr * 72 + lg * 8]);
    const s16x8 pa1 = *(const s16x8*)(&Ps[w][lr * 72 + 32 + lg * 8]);

    // O += P @ V   (V^T tile in LDS: row=d, col=key)
#pragma unroll
    for (int db = 0; db < 4; ++db) {
      const s16x8 vf0 = *(const s16x8*)(Vs + (db * 16 + lr) * 64 + lg * 8);
      const s16x8 vf1 = *(const s16x8*)(Vs + (db * 16 + lr) * 64 + 32 + lg * 8);
      oacc[db] = mfma16(pa0, vf0, oacc[db]);
      oacc[db] = mfma16(pa1, vf1, oacc[db]);
    }
  }

  // epilogue: normalize + store as [B, L, H*D] bf16
  const int b = bh >> 4, h = bh & 15;
#pragma unroll
  for (int r = 0; r < 4; ++r) {
    const float inv = 1.f / l_run[r];
    const int row = b * 2048 + qrow0 + r;
#pragma unroll
    for (int db = 0; db < 4; ++db)
      oup[row * 1024 + h * 64 + db * 16 + lr] = f2bf(oacc[db][r] * inv);
  }
}

extern "C" void kernel_launch(void* const* d_in, const int* in_sizes, int n_in,
                              void* d_out, int out_size, void* d_ws, size_t ws_size,
                              hipStream_t stream) {
  const float* x     = (const float*)d_in[0];
  const float* ab    = (const float*)d_in[1];
  const float* wqkv  = (const float*)d_in[2];
  const float* qbias = (const float*)d_in[3];
  const float* vbias = (const float*)d_in[4];
  const float* wproj = (const float*)d_in[5];
  const float* bproj = (const float*)d_in[6];
  float* out = (float*)d_out;

  // workspace layout (80 MB total)
  char* ws = (char*)d_ws;
  if (ws_size < 83886080u) return;  // refuse to corrupt memory
  u16* xb     = (u16*)(ws);              // 16 MB; reused as oup after QKV GEMM
  u16* wqkvb  = (u16*)(ws + 16777216);   // 6 MB
  u16* wprojb = (u16*)(ws + 23068672);   // 2 MB
  u16* biasb  = (u16*)(ws + 25165824);   // 8 MB
  u16* qbuf   = (u16*)(ws + 33554432);   // 16 MB  [B,H,L,D]
  u16* kbuf   = (u16*)(ws + 50331648);   // 16 MB  [B,H,L,D]
  u16* vtbuf  = (u16*)(ws + 67108864);   // 16 MB  [B,H,D,L]

  cvt<<<dim3(2048), dim3(256), 0, stream>>>(x, xb, 8388608 / 4);
  cvt<<<dim3(512),  dim3(256), 0, stream>>>(wqkv, wqkvb, 3145728 / 4);
  cvt<<<dim3(256),  dim3(256), 0, stream>>>(wproj, wprojb, 1048576 / 4);
  cvt<<<dim3(1024), dim3(256), 0, stream>>>(ab, biasb, 4194304 / 4);

  gemm_bt<0><<<dim3(24, 64), dim3(256), 0, stream>>>(
      xb, wqkvb, 8192, 3072, 1024, qbias, vbias, qbuf, kbuf, vtbuf, nullptr);

  flash_attn<<<dim3(32, 64), dim3(256), 0, stream>>>(qbuf, kbuf, vtbuf, biasb, xb);

  gemm_bt<1><<<dim3(8, 64), dim3(256), 0, stream>>>(
      xb, wprojb, 8192, 1024, 1024, bproj, nullptr, nullptr, nullptr, nullptr, out);
}

// Round 2
// 356.378 us; speedup vs baseline: 1.2083x; 1.2083x over previous
//
#include <hip/hip_runtime.h>
#include <hip/hip_bf16.h>

typedef unsigned short u16;
typedef unsigned int   u32;

using f32x4 = __attribute__((ext_vector_type(4))) float;
using s16x8 = __attribute__((ext_vector_type(8))) short;
using b16x8 = __attribute__((ext_vector_type(8))) __bf16;

#define LOG2E 1.44269504088896f
#define QSC   (0.03125f * LOG2E)   // SCALE * log2(e), folded into q

__device__ __forceinline__ f32x4 mfma16(s16x8 a, s16x8 b, f32x4 c) {
  return __builtin_amdgcn_mfma_f32_16x16x32_bf16(
      __builtin_bit_cast(b16x8, a), __builtin_bit_cast(b16x8, b), c, 0, 0, 0);
}

__device__ __forceinline__ u16 f2bf(float f) {
  u32 u = __builtin_bit_cast(u32, f);
  u = (u + 0x7FFFu + ((u >> 16) & 1u)) >> 16;
  return (u16)u;
}
__device__ __forceinline__ float bf2f(u16 b) {
  return __builtin_bit_cast(float, ((u32)b) << 16);
}
__device__ __forceinline__ float exp2_hw(float x) {
  float r;
  asm("v_exp_f32 %0, %1" : "=v"(r) : "v"(x));
  return r;
}

// async global->LDS, 16B per lane; LDS dest = wave-uniform base + lane*16
__device__ __forceinline__ void gload16(const void* g, void* l) {
  __builtin_amdgcn_global_load_lds(
      (const __attribute__((address_space(1))) u32*)g,
      (__attribute__((address_space(3))) u32*)l, 16, 0, 0);
}

// ---------------- fp32 -> bf16 convert (with optional scale) ----------------
__global__ void cvt(const float* __restrict__ in, u16* __restrict__ out, int n4,
                    float mul) {
  int i = blockIdx.x * blockDim.x + threadIdx.x;
  int stride = gridDim.x * blockDim.x;
  for (; i < n4; i += stride) {
    float4 v = ((const float4*)in)[i];
    ushort4 o;
    o.x = f2bf(v.x * mul); o.y = f2bf(v.y * mul);
    o.z = f2bf(v.z * mul); o.w = f2bf(v.w * mul);
    ((ushort4*)out)[i] = o;
  }
}

// ---------------- GEMM: C[M,N] = A[M,K] @ B[N,K]^T  (both bf16, row-major) ----
// EPI==0: qkv epilogue (q: (acc+q_bias)*QSC; k: acc; v: acc+v_bias; scatter to
//         q[B,H,L,D], k[B,H,L,D], vT[B,H,D,L], bf16)
// EPI==1: proj epilogue (add b_proj, fp32 out row-major [M,N])
template<int EPI>
__global__ __launch_bounds__(256)
void gemm_bt(const u16* __restrict__ A, const u16* __restrict__ Bm,
             int M, int N, int K,
             const float* __restrict__ bias0, const float* __restrict__ bias1,
             u16* __restrict__ oq, u16* __restrict__ ok, u16* __restrict__ ov,
             float* __restrict__ outf)
{
  __shared__ u16 As[128 * 32];
  __shared__ u16 Bs[128 * 32];

  const int tid  = threadIdx.x;
  const int w    = tid >> 6;
  const int lane = tid & 63;
  const int lr   = lane & 15;
  const int lg   = lane >> 4;
  const int wr   = w >> 1, wc = w & 1;

  const int bm = blockIdx.y, bn = blockIdx.x;

  f32x4 acc[4][4];
#pragma unroll
  for (int i = 0; i < 4; ++i)
#pragma unroll
    for (int j = 0; j < 4; ++j) acc[i][j] = (f32x4){0.f, 0.f, 0.f, 0.f};

  const int rowA = bm * 128 + (tid >> 2);
  const int rowB = bn * 128 + (tid >> 2);
  const int colk = (tid & 3) * 8;

  for (int kt = 0; kt < K; kt += 32) {
    __syncthreads();
    {
      const u16* ga = A  + (long)rowA * K + kt + colk;
      const u16* gb = Bm + (long)rowB * K + kt + colk;
      u16* la = As + w * 512;
      u16* lb = Bs + w * 512;
      gload16(ga,            la);
      gload16(ga + 64 * K,   la + 2048);
      gload16(gb,            lb);
      gload16(gb + 64 * K,   lb + 2048);
    }
    __syncthreads();

    s16x8 af[4], bfr[4];
#pragma unroll
    for (int mi = 0; mi < 4; ++mi)
      af[mi] = *(const s16x8*)(As + (wr * 64 + mi * 16 + lr) * 32 + lg * 8);
#pragma unroll
    for (int ni = 0; ni < 4; ++ni)
      bfr[ni] = *(const s16x8*)(Bs + (wc * 64 + ni * 16 + lr) * 32 + lg * 8);
#pragma unroll
    for (int mi = 0; mi < 4; ++mi)
#pragma unroll
      for (int ni = 0; ni < 4; ++ni)
        acc[mi][ni] = mfma16(af[mi], bfr[ni], acc[mi][ni]);
  }

  const int gm0 = bm * 128 + wr * 64;
  const int gn0 = bn * 128 + wc * 64;

#pragma unroll
  for (int mi = 0; mi < 4; ++mi) {
#pragma unroll
    for (int ni = 0; ni < 4; ++ni) {
      const int col  = gn0 + ni * 16 + lr;
      const int row0 = gm0 + mi * 16 + lg * 4;
      if (EPI == 0) {
        const int which = col >> 10;          // 0=q 1=k 2=v
        const int cj    = col & 1023;
        const float badd = (which == 0) ? bias0[cj] : (which == 2 ? bias1[cj] : 0.f);
        const int h = cj >> 6, d = cj & 63;
#pragma unroll
        for (int r = 0; r < 4; ++r) {
          const int rowg = row0 + r;           // = b*2048 + l
          const int b = rowg >> 11, l = rowg & 2047;
          const int bh = b * 16 + h;
          float val = acc[mi][ni][r] + badd;
          if (which == 0) val *= QSC;          // fold softmax scale+log2e into q
          const u16 o = f2bf(val);
          if (which == 0)      oq[(bh * 2048 + l) * 64 + d] = o;
          else if (which == 1) ok[(bh * 2048 + l) * 64 + d] = o;
          else                 ov[(bh * 64 + d) * 2048 + l] = o;   // transposed V
        }
      } else {
        const float badd = bias0[col];
#pragma unroll
        for (int r = 0; r < 4; ++r)
          outf[(long)(row0 + r) * N + col] = acc[mi][ni][r] + badd;
      }
    }
  }
}

// ---------------- flash attention ----------------
// grid: x = L/64 (q tiles), y = B*H.  256 threads = 4 waves, 16 q-rows/wave.
// LDS tiles Q/K/V are chunk-XOR-swizzled: 16B chunk c of row r lives at
// physical chunk c^(r&7).  global_load_lds writes linearly, so the *source*
// global address is pre-swizzled (rule: both-sides-or-neither).
__global__ __launch_bounds__(256)
void flash_attn(const u16* __restrict__ qbuf, const u16* __restrict__ kbuf,
                const u16* __restrict__ vtbuf, const u16* __restrict__ biasb,
                u16* __restrict__ oup)
{
  __shared__ u16 Qs[64 * 64];
  __shared__ u16 Ks[64 * 64];
  __shared__ u16 Vs[64 * 64];          // holds V^T tile: [d][key]
  __shared__ u16 Ps[4][16 * 72];       // per-wave P, padded stride 72 elems

  const int tid  = threadIdx.x;
  const int w    = tid >> 6;
  const int lane = tid & 63;
  const int lr   = lane & 15;
  const int lg   = lane >> 4;
  const int bh   = blockIdx.y;
  const int qb0  = blockIdx.x * 64;
  const int base = bh * (2048 * 64);

  // swizzled source chunk offset (u16 elems) for staging
  const int csrc = (((tid & 7) ^ ((tid >> 3) & 7)) * 8);
  const int srow = tid >> 3;            // staged row within 32-row half

  // stage Q tile (rows qb0..qb0+63, 64 elems each)
  gload16(qbuf + base + (qb0 + srow) * 64 + csrc,        Qs + w * 512);
  gload16(qbuf + base + (qb0 + 32 + srow) * 64 + csrc,   Qs + 2048 + w * 512);
  __syncthreads();

  const int swx = lr & 7;               // read-side swizzle (row&7 == lr&7 everywhere)
  const int qrow = w * 16 + lr;
  const int qc1 = (lg ^ swx) * 8, qc2 = ((lg ^ swx) ^ 4) * 8;
  const s16x8 qf0 = *(const s16x8*)(Qs + qrow * 64 + qc1);
  const s16x8 qf1 = *(const s16x8*)(Qs + qrow * 64 + qc2);

  float m_run[4], l_run[4];
  f32x4 oacc[4];
#pragma unroll
  for (int r = 0; r < 4; ++r) { m_run[r] = -1e30f; l_run[r] = 0.f; }
#pragma unroll
  for (int db = 0; db < 4; ++db) oacc[db] = (f32x4){0.f, 0.f, 0.f, 0.f};

  const int qrow0 = qb0 + w * 16 + lg * 4;
  const u16* bias_p = biasb + (long)qrow0 * 2048 + lr;   // advance by 64/iter

  for (int kt = 0; kt < 2048; kt += 64) {
    __syncthreads();
    gload16(kbuf + base + kt * 64 + srow * 64 + csrc,          Ks + w * 512);
    gload16(kbuf + base + kt * 64 + (32 + srow) * 64 + csrc,   Ks + 2048 + w * 512);
    gload16(vtbuf + base + srow * 2048 + kt + csrc,            Vs + w * 512);
    gload16(vtbuf + base + (32 + srow) * 2048 + kt + csrc,     Vs + 2048 + w * 512);

    // bias fragment -> accumulator init (bias already *log2e)
    f32x4 s[4];
#pragma unroll
    for (int kb = 0; kb < 4; ++kb)
#pragma unroll
      for (int r = 0; r < 4; ++r)
        s[kb][r] = bf2f(bias_p[r * 2048 + kt + kb * 16]);

    __syncthreads();

    // S' = bias' + (q*QSC) K^T   (already in log2 domain)
#pragma unroll
    for (int kb = 0; kb < 4; ++kb) {
      const int krow = kb * 16 + lr;
      const s16x8 kf0 = *(const s16x8*)(Ks + krow * 64 + qc1);
      const s16x8 kf1 = *(const s16x8*)(Ks + krow * 64 + qc2);
      s[kb] = mfma16(qf0, kf0, s[kb]);
      s[kb] = mfma16(qf1, kf1, s[kb]);
    }

    // online softmax in exp2 domain (rows live in the 16-lane column group)
    float mt[4] = {-1e30f, -1e30f, -1e30f, -1e30f};
#pragma unroll
    for (int kb = 0; kb < 4; ++kb)
#pragma unroll
      for (int r = 0; r < 4; ++r)
        mt[r] = fmaxf(mt[r], s[kb][r]);
#pragma unroll
    for (int xm = 1; xm < 16; xm <<= 1)
#pragma unroll
      for (int r = 0; r < 4; ++r)
        mt[r] = fmaxf(mt[r], __shfl_xor(mt[r], xm, 64));

    float scl[4], rs[4], p[4][4];
#pragma unroll
    for (int r = 0; r < 4; ++r) {
      const float mn = fmaxf(m_run[r], mt[r]);
      scl[r] = exp2_hw(m_run[r] - mn);
      m_run[r] = mn;
    }
#pragma unroll
    for (int kb = 0; kb < 4; ++kb)
#pragma unroll
      for (int r = 0; r < 4; ++r)
        p[kb][r] = exp2_hw(s[kb][r] - m_run[r]);
#pragma unroll
    for (int r = 0; r < 4; ++r) rs[r] = (p[0][r] + p[1][r]) + (p[2][r] + p[3][r]);
#pragma unroll
    for (int xm = 1; xm < 16; xm <<= 1)
#pragma unroll
      for (int r = 0; r < 4; ++r)
        rs[r] += __shfl_xor(rs[r], xm, 64);
#pragma unroll
    for (int r = 0; r < 4; ++r) l_run[r] = l_run[r] * scl[r] + rs[r];
#pragma unroll
    for (int db = 0; db < 4; ++db)
#pragma unroll
      for (int r = 0; r < 4; ++r)
        oacc[db][r] *= scl[r];

    // P -> LDS (wave-private), then read back as A-fragments
#pragma unroll
    for (int kb = 0; kb < 4; ++kb)
#pragma unroll
      for (int r = 0; r < 4; ++r)
        Ps[w][(lg * 4 + r) * 72 + kb * 16 + lr] = f2bf(p[kb][r]);
    asm volatile("s_waitcnt lgkmcnt(0)" ::: "memory");
    const s16x8 pa0 = *(const s16x8*)(&Ps[w][lr * 72 + lg * 8]);
    const s16x8 pa1 = *(const s16x8*)(&Ps[w][lr * 72 + 32 + lg * 8]);

    // O += P @ V   (V^T tile in LDS: row=d, col=key; swizzled like K)
#pragma unroll
    for (int db = 0; db < 4; ++db) {
      const int vrow = db * 16 + lr;
      const s16x8 vf0 = *(const s16x8*)(Vs + vrow * 64 + qc1);
      const s16x8 vf1 = *(const s16x8*)(Vs + vrow * 64 + qc2);
      oacc[db] = mfma16(pa0, vf0, oacc[db]);
      oacc[db] = mfma16(pa1, vf1, oacc[db]);
    }
  }

  // epilogue: normalize + store as [B, L, H*D] bf16
  const int b = bh >> 4, h = bh & 15;
#pragma unroll
  for (int r = 0; r < 4; ++r) {
    const float inv = 1.f / l_run[r];
    const int row = b * 2048 + qrow0 + r;
#pragma unroll
    for (int db = 0; db < 4; ++db)
      oup[row * 1024 + h * 64 + db * 16 + lr] = f2bf(oacc[db][r] * inv);
  }
}

extern "C" void kernel_launch(void* const* d_in, const int* in_sizes, int n_in,
                              void* d_out, int out_size, void* d_ws, size_t ws_size,
                              hipStream_t stream) {
  const float* x     = (const float*)d_in[0];
  const float* ab    = (const float*)d_in[1];
  const float* wqkv  = (const float*)d_in[2];
  const float* qbias = (const float*)d_in[3];
  const float* vbias = (const float*)d_in[4];
  const float* wproj = (const float*)d_in[5];
  const float* bproj = (const float*)d_in[6];
  float* out = (float*)d_out;

  // workspace layout (80 MB total)
  char* ws = (char*)d_ws;
  if (ws_size < 83886080u) return;  // refuse to corrupt memory
  u16* xb     = (u16*)(ws);              // 16 MB; reused as oup after QKV GEMM
  u16* wqkvb  = (u16*)(ws + 16777216);   // 6 MB
  u16* wprojb = (u16*)(ws + 23068672);   // 2 MB
  u16* biasb  = (u16*)(ws + 25165824);   // 8 MB  (attn_bias * log2e)
  u16* qbuf   = (u16*)(ws + 33554432);   // 16 MB  [B,H,L,D] (q pre-scaled)
  u16* kbuf   = (u16*)(ws + 50331648);   // 16 MB  [B,H,L,D]
  u16* vtbuf  = (u16*)(ws + 67108864);   // 16 MB  [B,H,D,L]

  cvt<<<dim3(2048), dim3(256), 0, stream>>>(x, xb, 8388608 / 4, 1.0f);
  cvt<<<dim3(512),  dim3(256), 0, stream>>>(wqkv, wqkvb, 3145728 / 4, 1.0f);
  cvt<<<dim3(256),  dim3(256), 0, stream>>>(wproj, wprojb, 1048576 / 4, 1.0f);
  cvt<<<dim3(1024), dim3(256), 0, stream>>>(ab, biasb, 4194304 / 4, LOG2E);

  gemm_bt<0><<<dim3(24, 64), dim3(256), 0, stream>>>(
      xb, wqkvb, 8192, 3072, 1024, qbias, vbias, qbuf, kbuf, vtbuf, nullptr);

  flash_attn<<<dim3(32, 64), dim3(256), 0, stream>>>(qbuf, kbuf, vtbuf, biasb, xb);

  gemm_bt<1><<<dim3(8, 64), dim3(256), 0, stream>>>(
      xb, wprojb, 8192, 1024, 1024, bproj, nullptr, nullptr, nullptr, nullptr, out);
}